// Round 10
// baseline (112.546 us; speedup 1.0000x reference)
//
#include <hip/hip_runtime.h>
#include <math.h>

#define NH 8
#define BITS_ 5
#define NB 40
#define TS 64
#define MAUG 27
#define CIN 64
#define HH 56
#define WW 56
#define NN 32
#define OCH 256
#define DK 576
#define DPM 603
#define HW (HH*WW)

#define UST 59             // 16B cells per (r,unit) row: L=0 pad, 1..56 data, 57 pad, 58 stagger
#define LO_OFF 7552        // dword offset of lo tile = 4*8*UST*4
#define SMEM_DW 15104      // 2 tiles * 4 rows * 8 units * UST * 4 dw = 60.4 KB

typedef __attribute__((ext_vector_type(4))) float f32x4;
typedef __attribute__((ext_vector_type(8))) _Float16 f16x8;
typedef union { uint4 u; f16x8 h; } fragh_u;

__device__ __forceinline__ unsigned int f16b(float v) {
    union { _Float16 h; unsigned short u; } cv;
    cv.h = (_Float16)v;
    return (unsigned int)cv.u;
}
__device__ __forceinline__ float f16tof(unsigned int b) {
    union { _Float16 h; unsigned short u; } cv;
    cv.u = (unsigned short)b;
    return (float)cv.h;
}

// ---------------- kP: all prep (aT, ctab, zero tallied, norm partials, weight pack) ----
__global__ void kP(const float* __restrict__ kern, const float* __restrict__ a,
                   float* __restrict__ aT, float* __restrict__ ctab,
                   int* __restrict__ tallied, float* __restrict__ normP,
                   unsigned short* __restrict__ whA,
                   unsigned short* __restrict__ vaH, unsigned short* __restrict__ vaL)
{
    const int bid = blockIdx.x;
    const int t = threadIdx.x;
    if (bid < 32) {                       // transpose a -> aT
        for (int idx = bid * 256 + t; idx < DPM * NB; idx += 32 * 256) {
            int d = idx / NB, j = idx - d * NB;
            aT[idx] = a[j * DPM + d];
        }
    } else if (bid == 32) {               // ctab + zero tallied
        for (int g = t; g < 9 * NB; g += 256) {
            int pat = g / NB, j = g - pat * NB;
            int ry = pat / 3, rx = pat % 3;
            float s = 0.f;
            for (int ky = 0; ky < 3; ++ky) {
                if (ry == 0 && ky == 0) continue;
                if (ry == 2 && ky == 2) continue;
                for (int kx = 0; kx < 3; ++kx) {
                    if (rx == 0 && kx == 0) continue;
                    if (rx == 2 && kx == 2) continue;
                    for (int mc = 0; mc < 3; ++mc)
                        s += a[j * DPM + DK + mc * 9 + ky * 3 + kx];
                }
            }
            ctab[g] = 0.5f * s;
        }
        for (int g = t; g < NH * TS; g += 256) tallied[g] = 0;
    } else if (bid < 37) {                // norm partials
        int g = (bid - 33) * 256 + t;     // 1024 = 256 oc * 4 parts
        int oc = g >> 2, part = g & 3;
        const float4* p = (const float4*)(kern + oc * DK + part * 144);
        float sq = 0.f;
        #pragma unroll 4
        for (int i = 0; i < 36; ++i) {
            float4 v = p[i];
            sq += v.x * v.x + v.y * v.y + v.z * v.z + v.w * v.w;
        }
        normP[g] = sq;
    } else {                              // weight packing (342 frags * 64 lanes)
        int idx = (bid - 37) * 256 + t;
        int f = idx >> 6, lane = idx & 63;
        if (f < 288) {                    // main conv: single f16 A-frags
            const int kidxG = f >> 4, mf = f & 15;
            const int tap = kidxG % 9, cc = kidxG / 9;
            const int oc = mf * 16 + (lane & 15);
            const int cbase = cc * 32 + (lane >> 4) * 8;
            unsigned int hs[8];
            #pragma unroll
            for (int j = 0; j < 8; ++j)
                hs[j] = f16b(kern[oc * DK + (cbase + j) * 9 + tap]);
            unsigned int* p = (unsigned int*)(whA + ((size_t)f * 64 + lane) * 8);
            #pragma unroll
            for (int w2 = 0; w2 < 4; ++w2)
                p[w2] = hs[2 * w2] | (hs[2 * w2 + 1] << 16);
        } else if (f < 342) {             // vote: f16 hi/lo A-frags
            const int fv = f - 288;
            const int kidxG = fv / 3, mfv = fv % 3;
            const int tap = kidxG % 9, cc = kidxG / 9;
            const int j = mfv * 16 + (lane & 15);
            const int cbase = cc * 32 + (lane >> 4) * 8;
            unsigned int hs[8], ls[8];
            #pragma unroll
            for (int jj = 0; jj < 8; ++jj) {
                float w = (j < NB) ? a[j * DPM + (cbase + jj) * 9 + tap] : 0.f;
                unsigned int h = f16b(w);
                unsigned int l = f16b(w - f16tof(h));
                hs[jj] = h; ls[jj] = l;
            }
            unsigned int* ph = (unsigned int*)(vaH + ((size_t)fv * 64 + lane) * 8);
            unsigned int* pl = (unsigned int*)(vaL + ((size_t)fv * 64 + lane) * 8);
            #pragma unroll
            for (int w2 = 0; w2 < 4; ++w2) {
                ph[w2] = hs[2 * w2] | (hs[2 * w2 + 1] << 16);
                pl[w2] = ls[2 * w2] | (ls[2 * w2 + 1] << 16);
            }
        }
    }
}

// ---------------- kH: hash kernel vectors, one block per oc -------------------------
__global__ void __launch_bounds__(256) kH(const float* __restrict__ kern,
        const float* __restrict__ aT, const float* __restrict__ normP,
        int* __restrict__ bucket_k)
{
    __shared__ float xs[DK];
    __shared__ float red[256];
    __shared__ float accR[3 * 41];
    __shared__ float proj[NB];
    const int t = threadIdx.x;
    const int lane = t & 63, ty = t >> 6;
    const int oc = blockIdx.x;

    red[t] = fmaxf(fmaxf(normP[t], normP[t + 256]), fmaxf(normP[t + 512], normP[t + 768]));
    __syncthreads();
    for (int s = 128; s > 0; s >>= 1) {
        if (t < s) red[t] = fmaxf(red[t], red[t + s]);
        __syncthreads();
    }
    const float scale = 0.83f / sqrtf(red[0]);
    for (int i = t; i < DK; i += 256) xs[i] = scale * kern[(size_t)oc * DK + i];
    __syncthreads();

    const int j = (lane < NB) ? lane : (NB - 1);
    float acc = 0.f, sq = 0.f;
    const int d0 = ty * 144;
    for (int d = d0; d < d0 + 144; ++d) {
        float xv = xs[d];
        sq += xv * xv;
        acc += xv * aT[d * NB + j];
    }
    if (ty > 0) {
        if (lane < NB) accR[(ty - 1) * 41 + lane] = acc;
        if (lane == NB) accR[(ty - 1) * 41 + 40] = sq;
    }
    __syncthreads();
    if (ty == 0 && lane < NB) {
        acc += (accR[lane] + accR[41 + lane]) + accR[82 + lane];
        sq += (accR[40] + accR[81]) + accR[122];
        float pv = sq;
        for (int m = 0; m < MAUG; ++m) {
            acc += pv * aT[(DK + m) * NB + lane];
            pv = pv * pv;
        }
        proj[lane] = acc;
    }
    __syncthreads();
    if (t < NH) {
        int b = 0;
        #pragma unroll
        for (int bb = 0; bb < BITS_; ++bb)
            if (proj[t * BITS_ + bb] > 0.f) b |= (1 << bb);
        bucket_k[t * OCH + oc] = b & (TS - 1);
    }
}

// ---------------- kM: single-pass 256-oc conv + vote (vote hoisted), 8 waves ----------
// grid (28, NN), block (64,8). Wave (mg=wid&3, ng=wid>>2): M=64 oc, overlapping
// n-tiles at col bases {0,16,32,40}. Vote runs as a separate loop after the main
// epilogue so its accumulators/loads don't inflate main-loop register pressure.
__global__ void __launch_bounds__(512, 4) kM(const float* __restrict__ x,
        const unsigned short* __restrict__ whA,
        const unsigned short* __restrict__ vaH, const unsigned short* __restrict__ vaL,
        const float* __restrict__ ctab, int* __restrict__ tallied,
        float* __restrict__ out)
{
    __shared__ unsigned int smem[SMEM_DW];
    const int lane = threadIdx.x, wid = threadIdx.y;
    const int y0 = blockIdx.x * 2, n = blockIdx.y;
    const int lcol = lane & 15, hi4 = lane >> 4;
    const int t = wid * 64 + lane;
    const int mg = wid & 3, ng = wid >> 2;
    const int colbase = (mg == 3) ? 40 : mg * 16;

    // zero pad cells: L=0 and L=57 for 4 rows x 8 units x 2 tiles
    if (t < 256) {
        const int tile = t >> 7, rem = t & 127;
        const int L = (rem & 1) ? 57 : 0;
        const int u = (rem >> 1) & 7, r = rem >> 4;
        *(uint4*)&smem[tile * LO_OFF + ((r * 8 + u) * UST + L) * 4] =
            make_uint4(0u, 0u, 0u, 0u);
    }

    // stage: wave (r=wid&3, half=wid>>2), thread col=lane; 4 units (32 ch), hi+lo
    {
        const int r = wid & 3, half = wid >> 2;
        const int y = y0 - 1 + r;
        const bool valid = (lane < WW) && (y >= 0) && (y < HH);
        const float* xb = x + (((size_t)n * CIN + half * 32) * HH + (valid ? y : 0)) * WW + lane;
        #pragma unroll
        for (int uu = 0; uu < 4; ++uu) {
            unsigned int dh[4], dl[4];
            #pragma unroll
            for (int dd = 0; dd < 4; ++dd) {
                float v0 = valid ? xb[(size_t)(uu * 8 + dd * 2) * HW] : 0.f;
                float v1 = valid ? xb[(size_t)(uu * 8 + dd * 2 + 1) * HW] : 0.f;
                unsigned int h0 = f16b(v0), h1 = f16b(v1);
                unsigned int l0 = f16b(v0 - f16tof(h0));
                unsigned int l1 = f16b(v1 - f16tof(h1));
                dh[dd] = h0 | (h1 << 16);
                dl[dd] = l0 | (l1 << 16);
            }
            if (lane < WW) {
                const int ad = ((r * 8 + half * 4 + uu) * UST + 1 + lane) * 4;
                *(uint4*)&smem[ad] = make_uint4(dh[0], dh[1], dh[2], dh[3]);
                *(uint4*)&smem[LO_OFF + ad] = make_uint4(dl[0], dl[1], dl[2], dl[3]);
            }
        }
    }
    __syncthreads();

    const uint4* wbase = (const uint4*)whA + (size_t)mg * 4 * 64 + lane;
    const int rowu = (ng * 8 + hi4) * UST + lcol;

    // ---- main K-loop: clean {prefetch A, 4x(b128 + 4 MFMA)} body --------------------
    {
        f32x4 acc[4][4];
        #pragma unroll
        for (int mf = 0; mf < 4; ++mf)
            #pragma unroll
            for (int nf = 0; nf < 4; ++nf)
                acc[mf][nf] = (f32x4){0.f, 0.f, 0.f, 0.f};

        fragh_u ahA[4], ahB[4];
        #pragma unroll
        for (int mf = 0; mf < 4; ++mf) ahA[mf].u = wbase[mf * 64];

        #pragma unroll
        for (int kidx = 0; kidx < 18; ++kidx) {
            // compile-time-resolved double buffer (loop fully unrolled)
            fragh_u* cur = (kidx & 1) ? ahB : ahA;
            fragh_u* nxt = (kidx & 1) ? ahA : ahB;
            if (kidx < 17) {
                #pragma unroll
                for (int mf = 0; mf < 4; ++mf)
                    nxt[mf].u = wbase[(kidx + 1) * 1024 + mf * 64];
            }
            const int cc = kidx / 9, tap = kidx % 9;
            const int ky = tap / 3, kx = tap % 3;
            #pragma unroll
            for (int nf = 0; nf < 4; ++nf) {
                const int nb = (nf == 3) ? 40 : nf * 16;
                const int ad = (rowu + (ky * 8 + cc * 4) * UST + nb + kx) * 4;
                fragh_u bh;
                bh.u = *(const uint4*)&smem[ad];
                acc[0][nf] = __builtin_amdgcn_mfma_f32_16x16x32_f16(cur[0].h, bh.h, acc[0][nf], 0, 0, 0);
                acc[1][nf] = __builtin_amdgcn_mfma_f32_16x16x32_f16(cur[1].h, bh.h, acc[1][nf], 0, 0, 0);
                acc[2][nf] = __builtin_amdgcn_mfma_f32_16x16x32_f16(cur[2].h, bh.h, acc[2][nf], 0, 0, 0);
                acc[3][nf] = __builtin_amdgcn_mfma_f32_16x16x32_f16(cur[3].h, bh.h, acc[3][nf], 0, 0, 0);
            }
        }

        // main epilogue (unmasked; kZ zeroes inactive channels after kC). cols < 56.
        const int yrow = y0 + ng;
        #pragma unroll
        for (int mf = 0; mf < 4; ++mf) {
            #pragma unroll
            for (int reg = 0; reg < 4; ++reg) {
                const int oc = (mg * 4 + mf) * 16 + hi4 * 4 + reg;
                float* ob = out + (((size_t)n * OCH + oc) * HH + yrow) * WW;
                #pragma unroll
                for (int nf = 0; nf < 4; ++nf) {
                    const int col = ((nf == 3) ? 40 : nf * 16) + lcol;
                    ob[col] = acc[mf][nf][reg];
                }
            }
        }
    }   // acc dies here -> registers free for the vote loop

    // ---- vote loop (bit-identical vacc accumulation order vs merged version) --------
    f32x4 vacc[3];
    vacc[0] = (f32x4){0.f, 0.f, 0.f, 0.f};
    vacc[1] = (f32x4){0.f, 0.f, 0.f, 0.f};
    vacc[2] = (f32x4){0.f, 0.f, 0.f, 0.f};
    {
        const uint4* vbH = (const uint4*)vaH + lane;
        const uint4* vbL = (const uint4*)vaL + lane;
        #pragma unroll
        for (int kidx = 0; kidx < 18; ++kidx) {
            const int cc = kidx / 9, tap = kidx % 9;
            const int ky = tap / 3, kx = tap % 3;
            const int ad = (rowu + (ky * 8 + cc * 4) * UST + colbase + kx) * 4;
            fragh_u bh, bl;
            bh.u = *(const uint4*)&smem[ad];
            bl.u = *(const uint4*)&smem[LO_OFF + ad];
            #pragma unroll
            for (int mfv = 0; mfv < 3; ++mfv) {
                fragh_u vh, vl;
                vh.u = vbH[(kidx * 3 + mfv) * 64];
                vl.u = vbL[(kidx * 3 + mfv) * 64];
                vacc[mfv] = __builtin_amdgcn_mfma_f32_16x16x32_f16(vh.h, bh.h, vacc[mfv], 0, 0, 0);
                vacc[mfv] = __builtin_amdgcn_mfma_f32_16x16x32_f16(vh.h, bl.h, vacc[mfv], 0, 0, 0);
                vacc[mfv] = __builtin_amdgcn_mfma_f32_16x16x32_f16(vl.h, bh.h, vacc[mfv], 0, 0, 0);
            }
        }
    }

    // vote epilogue (overlap px 40..47 double-written with identical values)
    __syncthreads();
    float* projT = (float*)smem;            // (row*64+px)*49 + j, max 5878 dw
    int* hist = (int*)&smem[6144];
    {
        const int px = colbase + lcol;
        #pragma unroll
        for (int mfv = 0; mfv < 3; ++mfv)
            #pragma unroll
            for (int reg = 0; reg < 4; ++reg)
                projT[(ng * 64 + px) * 49 + mfv * 16 + hi4 * 4 + reg] = vacc[mfv][reg];
    }
    hist[t] = 0;
    __syncthreads();
    if (t < 2 * WW) {
        const int row = t / WW, pxx = t - row * WW;
        const int yv = y0 + row;
        const int ry = (yv == 0) ? 0 : ((yv == HH - 1) ? 2 : 1);
        const int rx = (pxx == 0) ? 0 : ((pxx == WW - 1) ? 2 : 1);
        const float* ct = ctab + (ry * 3 + rx) * NB;
        const float* pr = projT + (row * 64 + pxx) * 49;
        #pragma unroll
        for (int h = 0; h < NH; ++h) {
            int b = 0;
            #pragma unroll
            for (int bb = 0; bb < BITS_; ++bb)
                if (pr[h * BITS_ + bb] + ct[h * BITS_ + bb] > 0.f) b |= (1 << bb);
            atomicAdd(&hist[h * TS + (b & (TS - 1))], 1);
        }
    }
    __syncthreads();
    {
        int v = hist[t];
        if (v) atomicAdd(&tallied[t], v);
    }
}

// ---------------- kC: argmax, mask, small outputs ----------------
__global__ void kC(const int* __restrict__ tallied, const int* __restrict__ bucket_k,
                   float* __restrict__ o_tallied, float* __restrict__ o_indices,
                   float* __restrict__ o_mask, int* __restrict__ mask_i)
{
    const int t = threadIdx.x;
    __shared__ int s_idx[NH];
    if (t < NH) {
        int best = tallied[t * TS];
        int bi = 0;
        for (int b = 1; b < TS; ++b) {
            int v = tallied[t * TS + b];
            if (v > best) { best = v; bi = b; }
        }
        s_idx[t] = bi;
        o_indices[t] = (float)bi;
    }
    for (int i = t; i < NH * TS; i += 256) o_tallied[i] = (float)tallied[i];
    __syncthreads();
    int mk = 0;
    #pragma unroll
    for (int hp = 0; hp < NH; ++hp) {
        int b = bucket_k[hp * OCH + t];
        #pragma unroll
        for (int h = 0; h < NH; ++h) mk |= (b == s_idx[h]) ? 1 : 0;
    }
    mask_i[t] = mk;
    o_mask[t] = (float)mk;
}

// ---------------- kZ: zero inactive output channels (all 256) ----------------
__global__ void __launch_bounds__(256) kZ(float* __restrict__ out,
                                          const int* __restrict__ mask_i)
{
    const int b = blockIdx.x;
    const int oc = b & (OCH - 1);
    if (mask_i[oc]) return;
    const int n = b >> 8;
    float4* o = (float4*)(out + ((size_t)n * OCH + oc) * HW);
    for (int i = threadIdx.x; i < HW / 4; i += 256)
        o[i] = make_float4(0.f, 0.f, 0.f, 0.f);
}

extern "C" void kernel_launch(void* const* d_in, const int* in_sizes, int n_in,
                              void* d_out, int out_size, void* d_ws, size_t ws_size,
                              hipStream_t stream)
{
    const float* x    = (const float*)d_in[0];
    const float* kern = (const float*)d_in[1];
    const float* a    = (const float*)d_in[2];

    float* out       = (float*)d_out;
    float* o_tallied = out + (size_t)NN * OCH * HW;
    float* o_indices = o_tallied + NH * TS;
    float* o_mask    = o_indices + NH;

    float* ws = (float*)d_ws;
    float* aT       = ws;                      // 24120 -> pad 24320
    float* ctab     = ws + 24320;              // 360 -> pad 384
    float* normP    = ws + 24704;              // 1024
    int*   tallied  = (int*)(ws + 25728);      // 512
    int*   bucket_k = (int*)(ws + 26240);      // 2048
    int*   mask_i   = (int*)(ws + 28288);      // 256
    unsigned short* whA = (unsigned short*)(ws + 28544);    // 73728 f
    unsigned short* vaH = (unsigned short*)(ws + 102272);   // 13824 f
    unsigned short* vaL = (unsigned short*)(ws + 116096);   // 13824 f

    kP<<<123, 256, 0, stream>>>(kern, a, aT, ctab, tallied, normP, whA, vaH, vaL);
    kH<<<OCH, 256, 0, stream>>>(kern, aT, normP, bucket_k);
    kM<<<dim3(28, NN), dim3(64, 8), 0, stream>>>(x, whA, vaH, vaL, ctab, tallied, out);
    kC<<<1, 256, 0, stream>>>(tallied, bucket_k, o_tallied, o_indices, o_mask, mask_i);
    kZ<<<NN * OCH, 256, 0, stream>>>(out, mask_i);
}

// Round 11
// 109.381 us; speedup vs baseline: 1.0289x; 1.0289x over previous
//
#include <hip/hip_runtime.h>
#include <math.h>

#define NH 8
#define BITS_ 5
#define NB 40
#define TS 64
#define MAUG 27
#define CIN 64
#define HH 56
#define WW 56
#define NN 32
#define OCH 256
#define DK 576
#define DPM 603
#define HW (HH*WW)

#define UST 59             // 16B cells per (r,unit) row: L=0 pad, 1..56 data, 57 pad, 58 stagger
#define LO_OFF 7552        // dword offset of lo tile = 4*8*UST*4
#define SMEM_DW 15104      // 2 tiles * 4 rows * 8 units * UST * 4 dw = 60.4 KB

typedef __attribute__((ext_vector_type(4))) float f32x4;
typedef __attribute__((ext_vector_type(8))) _Float16 f16x8;
typedef union { uint4 u; f16x8 h; } fragh_u;

__device__ __forceinline__ unsigned int f16b(float v) {
    union { _Float16 h; unsigned short u; } cv;
    cv.h = (_Float16)v;
    return (unsigned int)cv.u;
}
__device__ __forceinline__ float f16tof(unsigned int b) {
    union { _Float16 h; unsigned short u; } cv;
    cv.u = (unsigned short)b;
    return (float)cv.h;
}

// ---------------- kP: all prep (aT, ctab, zero tallied, norm partials, weight pack) ----
__global__ void kP(const float* __restrict__ kern, const float* __restrict__ a,
                   float* __restrict__ aT, float* __restrict__ ctab,
                   int* __restrict__ tallied, float* __restrict__ normP,
                   unsigned short* __restrict__ whA,
                   unsigned short* __restrict__ vaH, unsigned short* __restrict__ vaL)
{
    const int bid = blockIdx.x;
    const int t = threadIdx.x;
    if (bid < 32) {                       // transpose a -> aT
        for (int idx = bid * 256 + t; idx < DPM * NB; idx += 32 * 256) {
            int d = idx / NB, j = idx - d * NB;
            aT[idx] = a[j * DPM + d];
        }
    } else if (bid == 32) {               // ctab + zero tallied
        for (int g = t; g < 9 * NB; g += 256) {
            int pat = g / NB, j = g - pat * NB;
            int ry = pat / 3, rx = pat % 3;
            float s = 0.f;
            for (int ky = 0; ky < 3; ++ky) {
                if (ry == 0 && ky == 0) continue;
                if (ry == 2 && ky == 2) continue;
                for (int kx = 0; kx < 3; ++kx) {
                    if (rx == 0 && kx == 0) continue;
                    if (rx == 2 && kx == 2) continue;
                    for (int mc = 0; mc < 3; ++mc)
                        s += a[j * DPM + DK + mc * 9 + ky * 3 + kx];
                }
            }
            ctab[g] = 0.5f * s;
        }
        for (int g = t; g < NH * TS; g += 256) tallied[g] = 0;
    } else if (bid < 37) {                // norm partials
        int g = (bid - 33) * 256 + t;     // 1024 = 256 oc * 4 parts
        int oc = g >> 2, part = g & 3;
        const float4* p = (const float4*)(kern + oc * DK + part * 144);
        float sq = 0.f;
        #pragma unroll 4
        for (int i = 0; i < 36; ++i) {
            float4 v = p[i];
            sq += v.x * v.x + v.y * v.y + v.z * v.z + v.w * v.w;
        }
        normP[g] = sq;
    } else {                              // weight packing (342 frags * 64 lanes)
        int idx = (bid - 37) * 256 + t;
        int f = idx >> 6, lane = idx & 63;
        if (f < 288) {                    // main conv: single f16 A-frags
            const int kidxG = f >> 4, mf = f & 15;
            const int tap = kidxG % 9, cc = kidxG / 9;
            const int oc = mf * 16 + (lane & 15);
            const int cbase = cc * 32 + (lane >> 4) * 8;
            unsigned int hs[8];
            #pragma unroll
            for (int j = 0; j < 8; ++j)
                hs[j] = f16b(kern[oc * DK + (cbase + j) * 9 + tap]);
            unsigned int* p = (unsigned int*)(whA + ((size_t)f * 64 + lane) * 8);
            #pragma unroll
            for (int w2 = 0; w2 < 4; ++w2)
                p[w2] = hs[2 * w2] | (hs[2 * w2 + 1] << 16);
        } else if (f < 342) {             // vote: f16 hi/lo A-frags
            const int fv = f - 288;
            const int kidxG = fv / 3, mfv = fv % 3;
            const int tap = kidxG % 9, cc = kidxG / 9;
            const int j = mfv * 16 + (lane & 15);
            const int cbase = cc * 32 + (lane >> 4) * 8;
            unsigned int hs[8], ls[8];
            #pragma unroll
            for (int jj = 0; jj < 8; ++jj) {
                float w = (j < NB) ? a[j * DPM + (cbase + jj) * 9 + tap] : 0.f;
                unsigned int h = f16b(w);
                unsigned int l = f16b(w - f16tof(h));
                hs[jj] = h; ls[jj] = l;
            }
            unsigned int* ph = (unsigned int*)(vaH + ((size_t)fv * 64 + lane) * 8);
            unsigned int* pl = (unsigned int*)(vaL + ((size_t)fv * 64 + lane) * 8);
            #pragma unroll
            for (int w2 = 0; w2 < 4; ++w2) {
                ph[w2] = hs[2 * w2] | (hs[2 * w2 + 1] << 16);
                pl[w2] = ls[2 * w2] | (ls[2 * w2 + 1] << 16);
            }
        }
    }
}

// ---------------- kH: hash kernel vectors, one block per oc -------------------------
__global__ void __launch_bounds__(256) kH(const float* __restrict__ kern,
        const float* __restrict__ aT, const float* __restrict__ normP,
        int* __restrict__ bucket_k)
{
    __shared__ float xs[DK];
    __shared__ float red[256];
    __shared__ float accR[3 * 41];
    __shared__ float proj[NB];
    const int t = threadIdx.x;
    const int lane = t & 63, ty = t >> 6;
    const int oc = blockIdx.x;

    red[t] = fmaxf(fmaxf(normP[t], normP[t + 256]), fmaxf(normP[t + 512], normP[t + 768]));
    __syncthreads();
    for (int s = 128; s > 0; s >>= 1) {
        if (t < s) red[t] = fmaxf(red[t], red[t + s]);
        __syncthreads();
    }
    const float scale = 0.83f / sqrtf(red[0]);
    for (int i = t; i < DK; i += 256) xs[i] = scale * kern[(size_t)oc * DK + i];
    __syncthreads();

    const int j = (lane < NB) ? lane : (NB - 1);
    float acc = 0.f, sq = 0.f;
    const int d0 = ty * 144;
    for (int d = d0; d < d0 + 144; ++d) {
        float xv = xs[d];
        sq += xv * xv;
        acc += xv * aT[d * NB + j];
    }
    if (ty > 0) {
        if (lane < NB) accR[(ty - 1) * 41 + lane] = acc;
        if (lane == NB) accR[(ty - 1) * 41 + 40] = sq;
    }
    __syncthreads();
    if (ty == 0 && lane < NB) {
        acc += (accR[lane] + accR[41 + lane]) + accR[82 + lane];
        sq += (accR[40] + accR[81]) + accR[122];
        float pv = sq;
        for (int m = 0; m < MAUG; ++m) {
            acc += pv * aT[(DK + m) * NB + lane];
            pv = pv * pv;
        }
        proj[lane] = acc;
    }
    __syncthreads();
    if (t < NH) {
        int b = 0;
        #pragma unroll
        for (int bb = 0; bb < BITS_; ++bb)
            if (proj[t * BITS_ + bb] > 0.f) b |= (1 << bb);
        bucket_k[t * OCH + oc] = b & (TS - 1);
    }
}

// address of (kidx, col-tile-base nb) B-cell, dwords
#define ADX(kidx, nb) ((rowu + ((((kidx) % 9) / 3) * 8 + ((kidx) / 9) * 4) * UST + (nb) + (((kidx) % 9) % 3)) * 4)

// ---------------- kM: single-pass 256-oc conv + vote, software-pipelined --------------
// grid (28, NN), block (64,8). Wave (mg=wid&3, ng=wid>>2): M=64 oc, overlapping
// n-tiles at col bases {0,16,32,40}. Main loop flattened to 72 steps with depth-2
// LDS-B prefetch + 1-kidx A prefetch; vote loop flattened to 54 steps with depth-2
// global prefetch. Per-accumulator MFMA order identical to prior rounds.
__global__ void __launch_bounds__(512, 4) kM(const float* __restrict__ x,
        const unsigned short* __restrict__ whA,
        const unsigned short* __restrict__ vaH, const unsigned short* __restrict__ vaL,
        const float* __restrict__ ctab, int* __restrict__ tallied,
        float* __restrict__ out)
{
    __shared__ unsigned int smem[SMEM_DW];
    const int lane = threadIdx.x, wid = threadIdx.y;
    const int y0 = blockIdx.x * 2, n = blockIdx.y;
    const int lcol = lane & 15, hi4 = lane >> 4;
    const int t = wid * 64 + lane;
    const int mg = wid & 3, ng = wid >> 2;
    const int colbase = (mg == 3) ? 40 : mg * 16;
    const uint4* wbase = (const uint4*)whA + (size_t)mg * 4 * 64 + lane;
    const int rowu = (ng * 8 + hi4) * UST + lcol;

    // ---- issue first A-frag loads (kidx 0) before any staging work ------------------
    fragh_u ahA[4], ahB[4];
    #pragma unroll
    for (int mf = 0; mf < 4; ++mf) ahA[mf].u = wbase[mf * 64];

    // ---- staging: issue all 32 x-loads up front (clamped addresses), then convert ---
    {
        const int r = wid & 3, half = wid >> 2;
        const int y = y0 - 1 + r;
        const bool valid = (lane < WW) && (y >= 0) && (y < HH);
        const int colc = (lane < WW) ? lane : (WW - 1);
        const int yc = (y >= 0 && y < HH) ? y : 0;
        const float* xb = x + (((size_t)n * CIN + half * 32) * HH + yc) * WW + colc;
        float xv[32];
        #pragma unroll
        for (int i = 0; i < 32; ++i) xv[i] = xb[(size_t)i * HW];

        // zero pad cells while loads are in flight: L=0 and L=57, 4r x 8u x 2 tiles
        if (t < 256) {
            const int tile = t >> 7, rem = t & 127;
            const int L = (rem & 1) ? 57 : 0;
            const int u = (rem >> 1) & 7, rr = rem >> 4;
            *(uint4*)&smem[tile * LO_OFF + ((rr * 8 + u) * UST + L) * 4] =
                make_uint4(0u, 0u, 0u, 0u);
        }

        #pragma unroll
        for (int uu = 0; uu < 4; ++uu) {
            unsigned int dh[4], dl[4];
            #pragma unroll
            for (int dd = 0; dd < 4; ++dd) {
                float v0 = valid ? xv[uu * 8 + dd * 2] : 0.f;
                float v1 = valid ? xv[uu * 8 + dd * 2 + 1] : 0.f;
                unsigned int h0 = f16b(v0), h1 = f16b(v1);
                unsigned int l0 = f16b(v0 - f16tof(h0));
                unsigned int l1 = f16b(v1 - f16tof(h1));
                dh[dd] = h0 | (h1 << 16);
                dl[dd] = l0 | (l1 << 16);
            }
            if (lane < WW) {
                const int ad = ((r * 8 + half * 4 + uu) * UST + 1 + lane) * 4;
                *(uint4*)&smem[ad] = make_uint4(dh[0], dh[1], dh[2], dh[3]);
                *(uint4*)&smem[LO_OFF + ad] = make_uint4(dl[0], dl[1], dl[2], dl[3]);
            }
        }
    }
    __syncthreads();

    // ---- main K-loop: 72 flattened steps, depth-2 B prefetch ------------------------
    {
        f32x4 acc[4][4];
        #pragma unroll
        for (int mf = 0; mf < 4; ++mf)
            #pragma unroll
            for (int nf = 0; nf < 4; ++nf)
                acc[mf][nf] = (f32x4){0.f, 0.f, 0.f, 0.f};

        fragh_u bhP[3];
        bhP[0].u = *(const uint4*)&smem[ADX(0, 0)];
        bhP[1].u = *(const uint4*)&smem[ADX(0, 16)];

        #pragma unroll
        for (int step = 0; step < 72; ++step) {
            const int kidx = step >> 2, nf = step & 3;
            fragh_u* cur = (kidx & 1) ? ahB : ahA;
            fragh_u* nxt = (kidx & 1) ? ahA : ahB;
            if (nf == 0 && kidx < 17) {
                #pragma unroll
                for (int mf = 0; mf < 4; ++mf)
                    nxt[mf].u = wbase[(kidx + 1) * 1024 + mf * 64];
            }
            if (step + 2 < 72) {
                const int s2 = step + 2;
                const int k2 = s2 >> 2, nf2 = s2 & 3;
                const int nb2 = (nf2 == 3) ? 40 : nf2 * 16;
                bhP[s2 % 3].u = *(const uint4*)&smem[ADX(k2, nb2)];
            }
            const fragh_u bh = bhP[step % 3];
            acc[0][nf] = __builtin_amdgcn_mfma_f32_16x16x32_f16(cur[0].h, bh.h, acc[0][nf], 0, 0, 0);
            acc[1][nf] = __builtin_amdgcn_mfma_f32_16x16x32_f16(cur[1].h, bh.h, acc[1][nf], 0, 0, 0);
            acc[2][nf] = __builtin_amdgcn_mfma_f32_16x16x32_f16(cur[2].h, bh.h, acc[2][nf], 0, 0, 0);
            acc[3][nf] = __builtin_amdgcn_mfma_f32_16x16x32_f16(cur[3].h, bh.h, acc[3][nf], 0, 0, 0);
        }

        // main epilogue (unmasked; kZ zeroes inactive channels after kC). cols < 56.
        const int yrow = y0 + ng;
        #pragma unroll
        for (int mf = 0; mf < 4; ++mf) {
            #pragma unroll
            for (int reg = 0; reg < 4; ++reg) {
                const int oc = (mg * 4 + mf) * 16 + hi4 * 4 + reg;
                float* ob = out + (((size_t)n * OCH + oc) * HH + yrow) * WW;
                #pragma unroll
                for (int nf = 0; nf < 4; ++nf) {
                    const int col = ((nf == 3) ? 40 : nf * 16) + lcol;
                    ob[col] = acc[mf][nf][reg];
                }
            }
        }
    }   // acc dies -> registers free for the vote pipeline

    // ---- vote loop: 54 flattened steps, depth-2 global prefetch ---------------------
    f32x4 vacc[3];
    vacc[0] = (f32x4){0.f, 0.f, 0.f, 0.f};
    vacc[1] = (f32x4){0.f, 0.f, 0.f, 0.f};
    vacc[2] = (f32x4){0.f, 0.f, 0.f, 0.f};
    {
        const uint4* vbH = (const uint4*)vaH + lane;
        const uint4* vbL = (const uint4*)vaL + lane;
        fragh_u vh[3], vl[3];       // rotating depth-3 (prefetch 2 ahead)
        fragh_u bhV[2], blV[2];     // per-kidx ping-pong
        vh[0].u = vbH[0];   vl[0].u = vbL[0];
        vh[1].u = vbH[64];  vl[1].u = vbL[64];
        bhV[0].u = *(const uint4*)&smem[ADX(0, colbase)];
        blV[0].u = *(const uint4*)&smem[LO_OFF + ADX(0, colbase)];
        #pragma unroll
        for (int s = 0; s < 54; ++s) {
            const int kidx = s / 3, mfv = s % 3;
            const int b = kidx & 1;
            if (s + 2 < 54) {
                vh[(s + 2) % 3].u = vbH[(s + 2) * 64];
                vl[(s + 2) % 3].u = vbL[(s + 2) * 64];
            }
            if (mfv == 0 && kidx < 17) {
                bhV[b ^ 1].u = *(const uint4*)&smem[ADX(kidx + 1, colbase)];
                blV[b ^ 1].u = *(const uint4*)&smem[LO_OFF + ADX(kidx + 1, colbase)];
            }
            const fragh_u vhc = vh[s % 3], vlc = vl[s % 3];
            vacc[mfv] = __builtin_amdgcn_mfma_f32_16x16x32_f16(vhc.h, bhV[b].h, vacc[mfv], 0, 0, 0);
            vacc[mfv] = __builtin_amdgcn_mfma_f32_16x16x32_f16(vhc.h, blV[b].h, vacc[mfv], 0, 0, 0);
            vacc[mfv] = __builtin_amdgcn_mfma_f32_16x16x32_f16(vlc.h, bhV[b].h, vacc[mfv], 0, 0, 0);
        }
    }

    // vote epilogue (overlap px 40..47 double-written with identical values)
    __syncthreads();
    float* projT = (float*)smem;            // (row*64+px)*49 + j
    int* hist = (int*)&smem[6144];
    {
        const int px = colbase + lcol;
        #pragma unroll
        for (int mfv = 0; mfv < 3; ++mfv)
            #pragma unroll
            for (int reg = 0; reg < 4; ++reg)
                projT[(ng * 64 + px) * 49 + mfv * 16 + hi4 * 4 + reg] = vacc[mfv][reg];
    }
    hist[t] = 0;
    __syncthreads();
    if (t < 2 * WW) {
        const int row = t / WW, pxx = t - row * WW;
        const int yv = y0 + row;
        const int ry = (yv == 0) ? 0 : ((yv == HH - 1) ? 2 : 1);
        const int rx = (pxx == 0) ? 0 : ((pxx == WW - 1) ? 2 : 1);
        const float* ct = ctab + (ry * 3 + rx) * NB;
        const float* pr = projT + (row * 64 + pxx) * 49;
        #pragma unroll
        for (int h = 0; h < NH; ++h) {
            int b = 0;
            #pragma unroll
            for (int bb = 0; bb < BITS_; ++bb)
                if (pr[h * BITS_ + bb] + ct[h * BITS_ + bb] > 0.f) b |= (1 << bb);
            atomicAdd(&hist[h * TS + (b & (TS - 1))], 1);
        }
    }
    __syncthreads();
    {
        int v = hist[t];
        if (v) atomicAdd(&tallied[t], v);
    }
}

// ---------------- kC: argmax, mask, small outputs ----------------
__global__ void kC(const int* __restrict__ tallied, const int* __restrict__ bucket_k,
                   float* __restrict__ o_tallied, float* __restrict__ o_indices,
                   float* __restrict__ o_mask, int* __restrict__ mask_i)
{
    const int t = threadIdx.x;
    __shared__ int s_idx[NH];
    if (t < NH) {
        int best = tallied[t * TS];
        int bi = 0;
        for (int b = 1; b < TS; ++b) {
            int v = tallied[t * TS + b];
            if (v > best) { best = v; bi = b; }
        }
        s_idx[t] = bi;
        o_indices[t] = (float)bi;
    }
    for (int i = t; i < NH * TS; i += 256) o_tallied[i] = (float)tallied[i];
    __syncthreads();
    int mk = 0;
    #pragma unroll
    for (int hp = 0; hp < NH; ++hp) {
        int b = bucket_k[hp * OCH + t];
        #pragma unroll
        for (int h = 0; h < NH; ++h) mk |= (b == s_idx[h]) ? 1 : 0;
    }
    mask_i[t] = mk;
    o_mask[t] = (float)mk;
}

// ---------------- kZ: zero inactive output channels (all 256) ----------------
__global__ void __launch_bounds__(256) kZ(float* __restrict__ out,
                                          const int* __restrict__ mask_i)
{
    const int b = blockIdx.x;
    const int oc = b & (OCH - 1);
    if (mask_i[oc]) return;
    const int n = b >> 8;
    float4* o = (float4*)(out + ((size_t)n * OCH + oc) * HW);
    for (int i = threadIdx.x; i < HW / 4; i += 256)
        o[i] = make_float4(0.f, 0.f, 0.f, 0.f);
}

extern "C" void kernel_launch(void* const* d_in, const int* in_sizes, int n_in,
                              void* d_out, int out_size, void* d_ws, size_t ws_size,
                              hipStream_t stream)
{
    const float* x    = (const float*)d_in[0];
    const float* kern = (const float*)d_in[1];
    const float* a    = (const float*)d_in[2];

    float* out       = (float*)d_out;
    float* o_tallied = out + (size_t)NN * OCH * HW;
    float* o_indices = o_tallied + NH * TS;
    float* o_mask    = o_indices + NH;

    float* ws = (float*)d_ws;
    float* aT       = ws;                      // 24120 -> pad 24320
    float* ctab     = ws + 24320;              // 360 -> pad 384
    float* normP    = ws + 24704;              // 1024
    int*   tallied  = (int*)(ws + 25728);      // 512
    int*   bucket_k = (int*)(ws + 26240);      // 2048
    int*   mask_i   = (int*)(ws + 28288);      // 256
    unsigned short* whA = (unsigned short*)(ws + 28544);    // 73728 f
    unsigned short* vaH = (unsigned short*)(ws + 102272);   // 13824 f
    unsigned short* vaL = (unsigned short*)(ws + 116096);   // 13824 f

    kP<<<123, 256, 0, stream>>>(kern, a, aT, ctab, tallied, normP, whA, vaH, vaL);
    kH<<<OCH, 256, 0, stream>>>(kern, aT, normP, bucket_k);
    kM<<<dim3(28, NN), dim3(64, 8), 0, stream>>>(x, whA, vaH, vaL, ctab, tallied, out);
    kC<<<1, 256, 0, stream>>>(tallied, bucket_k, o_tallied, o_indices, o_mask, mask_i);
    kZ<<<NN * OCH, 256, 0, stream>>>(out, mask_i);
}

// Round 12
// 105.127 us; speedup vs baseline: 1.0706x; 1.0405x over previous
//
#include <hip/hip_runtime.h>
#include <math.h>

#define NH 8
#define BITS_ 5
#define NB 40
#define TS 64
#define MAUG 27
#define CIN 64
#define HH 56
#define WW 56
#define NN 32
#define OCH 256
#define DK 576
#define DPM 603
#define HW (HH*WW)

#define UST 59             // 16B cells per (r,unit) row: L=0 pad, 1..56 data, 57 pad, 58 stagger
#define LO_OFF 7552        // dword offset of lo tile = 4*8*UST*4
#define SMEM_DW 15104      // 2 tiles * 4 rows * 8 units * UST * 4 dw = 60.4 KB

typedef __attribute__((ext_vector_type(4))) float f32x4;
typedef __attribute__((ext_vector_type(8))) _Float16 f16x8;
typedef union { uint4 u; f16x8 h; } fragh_u;

__device__ __forceinline__ unsigned int f16b(float v) {
    union { _Float16 h; unsigned short u; } cv;
    cv.h = (_Float16)v;
    return (unsigned int)cv.u;
}
__device__ __forceinline__ float f16tof(unsigned int b) {
    union { _Float16 h; unsigned short u; } cv;
    cv.u = (unsigned short)b;
    return (float)cv.h;
}

// ---------------- kP: all prep (aT, ctab, zero tallied, norm partials, weight pack) ----
__global__ void kP(const float* __restrict__ kern, const float* __restrict__ a,
                   float* __restrict__ aT, float* __restrict__ ctab,
                   int* __restrict__ tallied, float* __restrict__ normP,
                   unsigned short* __restrict__ whA,
                   unsigned short* __restrict__ vaH, unsigned short* __restrict__ vaL)
{
    const int bid = blockIdx.x;
    const int t = threadIdx.x;
    if (bid < 32) {                       // transpose a -> aT
        for (int idx = bid * 256 + t; idx < DPM * NB; idx += 32 * 256) {
            int d = idx / NB, j = idx - d * NB;
            aT[idx] = a[j * DPM + d];
        }
    } else if (bid == 32) {               // ctab + zero tallied
        for (int g = t; g < 9 * NB; g += 256) {
            int pat = g / NB, j = g - pat * NB;
            int ry = pat / 3, rx = pat % 3;
            float s = 0.f;
            for (int ky = 0; ky < 3; ++ky) {
                if (ry == 0 && ky == 0) continue;
                if (ry == 2 && ky == 2) continue;
                for (int kx = 0; kx < 3; ++kx) {
                    if (rx == 0 && kx == 0) continue;
                    if (rx == 2 && kx == 2) continue;
                    for (int mc = 0; mc < 3; ++mc)
                        s += a[j * DPM + DK + mc * 9 + ky * 3 + kx];
                }
            }
            ctab[g] = 0.5f * s;
        }
        for (int g = t; g < NH * TS; g += 256) tallied[g] = 0;
    } else if (bid < 37) {                // norm partials
        int g = (bid - 33) * 256 + t;     // 1024 = 256 oc * 4 parts
        int oc = g >> 2, part = g & 3;
        const float4* p = (const float4*)(kern + oc * DK + part * 144);
        float sq = 0.f;
        #pragma unroll 4
        for (int i = 0; i < 36; ++i) {
            float4 v = p[i];
            sq += v.x * v.x + v.y * v.y + v.z * v.z + v.w * v.w;
        }
        normP[g] = sq;
    } else {                              // weight packing (342 frags * 64 lanes)
        int idx = (bid - 37) * 256 + t;
        int f = idx >> 6, lane = idx & 63;
        if (f < 288) {                    // main conv: single f16 A-frags
            const int kidxG = f >> 4, mf = f & 15;
            const int tap = kidxG % 9, cc = kidxG / 9;
            const int oc = mf * 16 + (lane & 15);
            const int cbase = cc * 32 + (lane >> 4) * 8;
            unsigned int hs[8];
            #pragma unroll
            for (int j = 0; j < 8; ++j)
                hs[j] = f16b(kern[oc * DK + (cbase + j) * 9 + tap]);
            unsigned int* p = (unsigned int*)(whA + ((size_t)f * 64 + lane) * 8);
            #pragma unroll
            for (int w2 = 0; w2 < 4; ++w2)
                p[w2] = hs[2 * w2] | (hs[2 * w2 + 1] << 16);
        } else if (f < 342) {             // vote: f16 hi/lo A-frags
            const int fv = f - 288;
            const int kidxG = fv / 3, mfv = fv % 3;
            const int tap = kidxG % 9, cc = kidxG / 9;
            const int j = mfv * 16 + (lane & 15);
            const int cbase = cc * 32 + (lane >> 4) * 8;
            unsigned int hs[8], ls[8];
            #pragma unroll
            for (int jj = 0; jj < 8; ++jj) {
                float w = (j < NB) ? a[j * DPM + (cbase + jj) * 9 + tap] : 0.f;
                unsigned int h = f16b(w);
                unsigned int l = f16b(w - f16tof(h));
                hs[jj] = h; ls[jj] = l;
            }
            unsigned int* ph = (unsigned int*)(vaH + ((size_t)fv * 64 + lane) * 8);
            unsigned int* pl = (unsigned int*)(vaL + ((size_t)fv * 64 + lane) * 8);
            #pragma unroll
            for (int w2 = 0; w2 < 4; ++w2) {
                ph[w2] = hs[2 * w2] | (hs[2 * w2 + 1] << 16);
                pl[w2] = ls[2 * w2] | (ls[2 * w2 + 1] << 16);
            }
        }
    }
}

// ---------------- kH: hash kernel vectors, one block per oc -------------------------
__global__ void __launch_bounds__(256) kH(const float* __restrict__ kern,
        const float* __restrict__ aT, const float* __restrict__ normP,
        int* __restrict__ bucket_k)
{
    __shared__ float xs[DK];
    __shared__ float red[256];
    __shared__ float accR[3 * 41];
    __shared__ float proj[NB];
    const int t = threadIdx.x;
    const int lane = t & 63, ty = t >> 6;
    const int oc = blockIdx.x;

    red[t] = fmaxf(fmaxf(normP[t], normP[t + 256]), fmaxf(normP[t + 512], normP[t + 768]));
    __syncthreads();
    for (int s = 128; s > 0; s >>= 1) {
        if (t < s) red[t] = fmaxf(red[t], red[t + s]);
        __syncthreads();
    }
    const float scale = 0.83f / sqrtf(red[0]);
    for (int i = t; i < DK; i += 256) xs[i] = scale * kern[(size_t)oc * DK + i];
    __syncthreads();

    const int j = (lane < NB) ? lane : (NB - 1);
    float acc = 0.f, sq = 0.f;
    const int d0 = ty * 144;
    for (int d = d0; d < d0 + 144; ++d) {
        float xv = xs[d];
        sq += xv * xv;
        acc += xv * aT[d * NB + j];
    }
    if (ty > 0) {
        if (lane < NB) accR[(ty - 1) * 41 + lane] = acc;
        if (lane == NB) accR[(ty - 1) * 41 + 40] = sq;
    }
    __syncthreads();
    if (ty == 0 && lane < NB) {
        acc += (accR[lane] + accR[41 + lane]) + accR[82 + lane];
        sq += (accR[40] + accR[81]) + accR[122];
        float pv = sq;
        for (int m = 0; m < MAUG; ++m) {
            acc += pv * aT[(DK + m) * NB + lane];
            pv = pv * pv;
        }
        proj[lane] = acc;
    }
    __syncthreads();
    if (t < NH) {
        int b = 0;
        #pragma unroll
        for (int bb = 0; bb < BITS_; ++bb)
            if (proj[t * BITS_ + bb] > 0.f) b |= (1 << bb);
        bucket_k[t * OCH + oc] = b & (TS - 1);
    }
}

// address of (kidx, col-tile-base nb) B-cell, dwords
#define ADX(kidx, nb) ((rowu + ((((kidx) % 9) / 3) * 8 + ((kidx) / 9) * 4) * UST + (nb) + (((kidx) % 9) % 3)) * 4)

// ---------------- kM: single-pass 256-oc conv + vote, pipelined + swizzled -----------
// grid (28, NN) remapped via bijective XCD swizzle (896 = 8 XCDs x 112 tiles): XCD k
// processes 4 whole images -> x+weights fit its 4 MB L2. Per-accumulator MFMA order
// identical to prior rounds (bit-identical outputs). setprio(1) wraps MFMA clusters.
__global__ void __launch_bounds__(512, 4) kM(const float* __restrict__ x,
        const unsigned short* __restrict__ whA,
        const unsigned short* __restrict__ vaH, const unsigned short* __restrict__ vaL,
        const float* __restrict__ ctab, int* __restrict__ tallied,
        float* __restrict__ out)
{
    __shared__ unsigned int smem[SMEM_DW];
    const int lane = threadIdx.x, wid = threadIdx.y;
    const int id = blockIdx.y * 28 + blockIdx.x;
    const int swz = (id & 7) * 112 + (id >> 3);      // bijective: 896 = 8*112
    const int n = swz / 28;
    const int y0 = (swz - n * 28) * 2;
    const int lcol = lane & 15, hi4 = lane >> 4;
    const int t = wid * 64 + lane;
    const int mg = wid & 3, ng = wid >> 2;
    const int colbase = (mg == 3) ? 40 : mg * 16;
    const uint4* wbase = (const uint4*)whA + (size_t)mg * 4 * 64 + lane;
    const int rowu = (ng * 8 + hi4) * UST + lcol;

    // ---- issue first A-frag loads (kidx 0) before any staging work ------------------
    fragh_u ahA[4], ahB[4];
    #pragma unroll
    for (int mf = 0; mf < 4; ++mf) ahA[mf].u = wbase[mf * 64];

    // ---- staging: issue all 32 x-loads up front (clamped addresses), then convert ---
    {
        const int r = wid & 3, half = wid >> 2;
        const int y = y0 - 1 + r;
        const bool valid = (lane < WW) && (y >= 0) && (y < HH);
        const int colc = (lane < WW) ? lane : (WW - 1);
        const int yc = (y >= 0 && y < HH) ? y : 0;
        const float* xb = x + (((size_t)n * CIN + half * 32) * HH + yc) * WW + colc;
        float xv[32];
        #pragma unroll
        for (int i = 0; i < 32; ++i) xv[i] = xb[(size_t)i * HW];

        // zero pad cells while loads are in flight: L=0 and L=57, 4r x 8u x 2 tiles
        if (t < 256) {
            const int tile = t >> 7, rem = t & 127;
            const int L = (rem & 1) ? 57 : 0;
            const int u = (rem >> 1) & 7, rr = rem >> 4;
            *(uint4*)&smem[tile * LO_OFF + ((rr * 8 + u) * UST + L) * 4] =
                make_uint4(0u, 0u, 0u, 0u);
        }

        #pragma unroll
        for (int uu = 0; uu < 4; ++uu) {
            unsigned int dh[4], dl[4];
            #pragma unroll
            for (int dd = 0; dd < 4; ++dd) {
                float v0 = valid ? xv[uu * 8 + dd * 2] : 0.f;
                float v1 = valid ? xv[uu * 8 + dd * 2 + 1] : 0.f;
                unsigned int h0 = f16b(v0), h1 = f16b(v1);
                unsigned int l0 = f16b(v0 - f16tof(h0));
                unsigned int l1 = f16b(v1 - f16tof(h1));
                dh[dd] = h0 | (h1 << 16);
                dl[dd] = l0 | (l1 << 16);
            }
            if (lane < WW) {
                const int ad = ((r * 8 + half * 4 + uu) * UST + 1 + lane) * 4;
                *(uint4*)&smem[ad] = make_uint4(dh[0], dh[1], dh[2], dh[3]);
                *(uint4*)&smem[LO_OFF + ad] = make_uint4(dl[0], dl[1], dl[2], dl[3]);
            }
        }
    }
    __syncthreads();

    // ---- main K-loop: 72 flattened steps, depth-2 B prefetch ------------------------
    {
        f32x4 acc[4][4];
        #pragma unroll
        for (int mf = 0; mf < 4; ++mf)
            #pragma unroll
            for (int nf = 0; nf < 4; ++nf)
                acc[mf][nf] = (f32x4){0.f, 0.f, 0.f, 0.f};

        fragh_u bhP[3];
        bhP[0].u = *(const uint4*)&smem[ADX(0, 0)];
        bhP[1].u = *(const uint4*)&smem[ADX(0, 16)];

        #pragma unroll
        for (int step = 0; step < 72; ++step) {
            const int kidx = step >> 2, nf = step & 3;
            fragh_u* cur = (kidx & 1) ? ahB : ahA;
            fragh_u* nxt = (kidx & 1) ? ahA : ahB;
            if (nf == 0 && kidx < 17) {
                #pragma unroll
                for (int mf = 0; mf < 4; ++mf)
                    nxt[mf].u = wbase[(kidx + 1) * 1024 + mf * 64];
            }
            if (step + 2 < 72) {
                const int s2 = step + 2;
                const int k2 = s2 >> 2, nf2 = s2 & 3;
                const int nb2 = (nf2 == 3) ? 40 : nf2 * 16;
                bhP[s2 % 3].u = *(const uint4*)&smem[ADX(k2, nb2)];
            }
            const fragh_u bh = bhP[step % 3];
            __builtin_amdgcn_s_setprio(1);
            acc[0][nf] = __builtin_amdgcn_mfma_f32_16x16x32_f16(cur[0].h, bh.h, acc[0][nf], 0, 0, 0);
            acc[1][nf] = __builtin_amdgcn_mfma_f32_16x16x32_f16(cur[1].h, bh.h, acc[1][nf], 0, 0, 0);
            acc[2][nf] = __builtin_amdgcn_mfma_f32_16x16x32_f16(cur[2].h, bh.h, acc[2][nf], 0, 0, 0);
            acc[3][nf] = __builtin_amdgcn_mfma_f32_16x16x32_f16(cur[3].h, bh.h, acc[3][nf], 0, 0, 0);
            __builtin_amdgcn_s_setprio(0);
        }

        // main epilogue (unmasked; kCZ zeroes inactive channels). cols < 56.
        const int yrow = y0 + ng;
        #pragma unroll
        for (int mf = 0; mf < 4; ++mf) {
            #pragma unroll
            for (int reg = 0; reg < 4; ++reg) {
                const int oc = (mg * 4 + mf) * 16 + hi4 * 4 + reg;
                float* ob = out + (((size_t)n * OCH + oc) * HH + yrow) * WW;
                #pragma unroll
                for (int nf = 0; nf < 4; ++nf) {
                    const int col = ((nf == 3) ? 40 : nf * 16) + lcol;
                    ob[col] = acc[mf][nf][reg];
                }
            }
        }
    }   // acc dies -> registers free for the vote pipeline

    // ---- vote loop: 54 flattened steps, depth-2 global prefetch ---------------------
    f32x4 vacc[3];
    vacc[0] = (f32x4){0.f, 0.f, 0.f, 0.f};
    vacc[1] = (f32x4){0.f, 0.f, 0.f, 0.f};
    vacc[2] = (f32x4){0.f, 0.f, 0.f, 0.f};
    {
        const uint4* vbH = (const uint4*)vaH + lane;
        const uint4* vbL = (const uint4*)vaL + lane;
        fragh_u vh[3], vl[3];       // rotating depth-3 (prefetch 2 ahead)
        fragh_u bhV[2], blV[2];     // per-kidx ping-pong
        vh[0].u = vbH[0];   vl[0].u = vbL[0];
        vh[1].u = vbH[64];  vl[1].u = vbL[64];
        bhV[0].u = *(const uint4*)&smem[ADX(0, colbase)];
        blV[0].u = *(const uint4*)&smem[LO_OFF + ADX(0, colbase)];
        #pragma unroll
        for (int s = 0; s < 54; ++s) {
            const int kidx = s / 3, mfv = s % 3;
            const int b = kidx & 1;
            if (s + 2 < 54) {
                vh[(s + 2) % 3].u = vbH[(s + 2) * 64];
                vl[(s + 2) % 3].u = vbL[(s + 2) * 64];
            }
            if (mfv == 0 && kidx < 17) {
                bhV[b ^ 1].u = *(const uint4*)&smem[ADX(kidx + 1, colbase)];
                blV[b ^ 1].u = *(const uint4*)&smem[LO_OFF + ADX(kidx + 1, colbase)];
            }
            const fragh_u vhc = vh[s % 3], vlc = vl[s % 3];
            __builtin_amdgcn_s_setprio(1);
            vacc[mfv] = __builtin_amdgcn_mfma_f32_16x16x32_f16(vhc.h, bhV[b].h, vacc[mfv], 0, 0, 0);
            vacc[mfv] = __builtin_amdgcn_mfma_f32_16x16x32_f16(vhc.h, blV[b].h, vacc[mfv], 0, 0, 0);
            vacc[mfv] = __builtin_amdgcn_mfma_f32_16x16x32_f16(vlc.h, bhV[b].h, vacc[mfv], 0, 0, 0);
            __builtin_amdgcn_s_setprio(0);
        }
    }

    // vote epilogue (overlap px 40..47 double-written with identical values)
    __syncthreads();
    float* projT = (float*)smem;            // (row*64+px)*49 + j
    int* hist = (int*)&smem[6144];
    {
        const int px = colbase + lcol;
        #pragma unroll
        for (int mfv = 0; mfv < 3; ++mfv)
            #pragma unroll
            for (int reg = 0; reg < 4; ++reg)
                projT[(ng * 64 + px) * 49 + mfv * 16 + hi4 * 4 + reg] = vacc[mfv][reg];
    }
    hist[t] = 0;
    __syncthreads();
    if (t < 2 * WW) {
        const int row = t / WW, pxx = t - row * WW;
        const int yv = y0 + row;
        const int ry = (yv == 0) ? 0 : ((yv == HH - 1) ? 2 : 1);
        const int rx = (pxx == 0) ? 0 : ((pxx == WW - 1) ? 2 : 1);
        const float* ct = ctab + (ry * 3 + rx) * NB;
        const float* pr = projT + (row * 64 + pxx) * 49;
        #pragma unroll
        for (int h = 0; h < NH; ++h) {
            int b = 0;
            #pragma unroll
            for (int bb = 0; bb < BITS_; ++bb)
                if (pr[h * BITS_ + bb] + ct[h * BITS_ + bb] > 0.f) b |= (1 << bb);
            atomicAdd(&hist[h * TS + (b & (TS - 1))], 1);
        }
    }
    __syncthreads();
    {
        int v = hist[t];
        if (v) atomicAdd(&tallied[t], v);
    }
}

// ---------------- kCZ: argmax + mask + small outputs + zero inactive channels --------
// grid NN*OCH. Each block redundantly computes the per-hash argmax (parallel
// first-max reduction == jnp.argmax semantics), then its own oc's mask; block 0
// additionally writes o_tallied / o_indices / o_mask.
__global__ void __launch_bounds__(256) kCZ(const int* __restrict__ tallied,
        const int* __restrict__ bucket_k, float* __restrict__ o_tallied,
        float* __restrict__ o_indices, float* __restrict__ o_mask,
        float* __restrict__ out)
{
    __shared__ int s_idx[NH];
    __shared__ int s_mk;
    const int t = threadIdx.x;
    {   // parallel first-max argmax: h = t>>5 (8 groups of 32 lanes), j = t&31
        const int h = t >> 5, j = t & 31;
        int v1 = tallied[h * TS + j], v2 = tallied[h * TS + 32 + j];
        int v, idx;
        if (v2 > v1) { v = v2; idx = 32 + j; } else { v = v1; idx = j; }
        #pragma unroll
        for (int s = 16; s > 0; s >>= 1) {
            int ov = __shfl_down(v, s, 32);
            int oi = __shfl_down(idx, s, 32);
            if (ov > v || (ov == v && oi < idx)) { v = ov; idx = oi; }
        }
        if (j == 0) s_idx[h] = idx;
    }
    __syncthreads();
    const int oc = blockIdx.x & (OCH - 1);
    const int n = blockIdx.x >> 8;
    if (t == 0) {
        int mk = 0;
        #pragma unroll
        for (int hp = 0; hp < NH; ++hp) {
            int b = bucket_k[hp * OCH + oc];
            #pragma unroll
            for (int h = 0; h < NH; ++h) mk |= (b == s_idx[h]) ? 1 : 0;
        }
        s_mk = mk;
    }
    if (blockIdx.x == 0) {
        for (int i = t; i < NH * TS; i += 256) o_tallied[i] = (float)tallied[i];
        if (t < NH) o_indices[t] = (float)s_idx[t];
        {
            int mk = 0;
            #pragma unroll
            for (int hp = 0; hp < NH; ++hp) {
                int b = bucket_k[hp * OCH + t];
                #pragma unroll
                for (int h = 0; h < NH; ++h) mk |= (b == s_idx[h]) ? 1 : 0;
            }
            o_mask[t] = (float)mk;
        }
    }
    __syncthreads();
    if (s_mk) return;
    float4* o = (float4*)(out + ((size_t)n * OCH + oc) * HW);
    for (int i = t; i < HW / 4; i += 256)
        o[i] = make_float4(0.f, 0.f, 0.f, 0.f);
}

extern "C" void kernel_launch(void* const* d_in, const int* in_sizes, int n_in,
                              void* d_out, int out_size, void* d_ws, size_t ws_size,
                              hipStream_t stream)
{
    const float* x    = (const float*)d_in[0];
    const float* kern = (const float*)d_in[1];
    const float* a    = (const float*)d_in[2];

    float* out       = (float*)d_out;
    float* o_tallied = out + (size_t)NN * OCH * HW;
    float* o_indices = o_tallied + NH * TS;
    float* o_mask    = o_indices + NH;

    float* ws = (float*)d_ws;
    float* aT       = ws;                      // 24120 -> pad 24320
    float* ctab     = ws + 24320;              // 360 -> pad 384
    float* normP    = ws + 24704;              // 1024
    int*   tallied  = (int*)(ws + 25728);      // 512
    int*   bucket_k = (int*)(ws + 26240);      // 2048
    unsigned short* whA = (unsigned short*)(ws + 28544);    // 73728 f
    unsigned short* vaH = (unsigned short*)(ws + 102272);   // 13824 f
    unsigned short* vaL = (unsigned short*)(ws + 116096);   // 13824 f

    kP<<<123, 256, 0, stream>>>(kern, a, aT, ctab, tallied, normP, whA, vaH, vaL);
    kH<<<OCH, 256, 0, stream>>>(kern, aT, normP, bucket_k);
    kM<<<dim3(28, NN), dim3(64, 8), 0, stream>>>(x, whA, vaH, vaL, ctab, tallied, out);
    kCZ<<<NN * OCH, 256, 0, stream>>>(tallied, bucket_k, o_tallied, o_indices, o_mask, out);
}